// Round 1
// baseline (311.918 us; speedup 1.0000x reference)
//
#include <hip/hip_runtime.h>
#include <math.h>

#define N 2
#define C 19
#define H 512
#define W 512
#define PADC 50
#define HC 412
#define WC 412
#define S 8192
#define CP 20            // padded channels (16B-aligned rows)
#define NCHUNK 8
#define CHUNK (S / NCHUNK)   // 1024
#define STILE 256
#define TT 128           // t rows staged in LDS per iteration
#define EPSF 1e-6f

// P[n][s][c] = output[n, c, 50 + sample[s]/412, 50 + sample[s]%412]
__global__ void gather_k(const float* __restrict__ out4d,
                         const int* __restrict__ sample,
                         float* __restrict__ P) {
    int idx = blockIdx.x * blockDim.x + threadIdx.x;   // 0 .. N*S-1
    if (idx >= N * S) return;
    int nn = idx / S;
    int s  = idx - nn * S;
    int smp = sample[s];
    int row = smp / WC;
    int col = smp - row * WC;
    int h = PADC + row, w = PADC + col;
    const float* base = out4d + ((size_t)nn * C) * H * W + (size_t)h * W + w;
    float* p = P + ((size_t)nn * S + s) * CP;
    #pragma unroll
    for (int c = 0; c < C; ++c) p[c] = base[(size_t)c * (H * W)];
    p[19] = 0.f;
}

// per (n, s, t-chunk): best dot + its (lowest) t index over the chunk
__global__ __launch_bounds__(256) void argmax_k(const float* __restrict__ P,
                                                float* __restrict__ pmax,
                                                int* __restrict__ pidx) {
    __shared__ float tile[TT * CP];   // 10 KiB
    int b = blockIdx.x;
    int chunk = b % NCHUNK;
    int stile = (b / NCHUNK) % (S / STILE);
    int nn = b / (NCHUNK * (S / STILE));
    int tid = threadIdx.x;
    int s = stile * STILE + tid;
    const float* Pn = P + (size_t)nn * S * CP;

    float ps[C];
    #pragma unroll
    for (int c = 0; c < C; ++c) ps[c] = Pn[(size_t)s * CP + c];

    float best = -INFINITY;
    int bi = chunk * CHUNK;
    int t0 = chunk * CHUNK;

    for (int tb = 0; tb < CHUNK; tb += TT) {
        // cooperative stage: TT rows * CP floats = 640 contiguous float4
        const float4* src = (const float4*)(Pn + (size_t)(t0 + tb) * CP);
        float4* dst = (float4*)tile;
        for (int f = tid; f < TT * CP / 4; f += 256) dst[f] = src[f];
        __syncthreads();

        for (int tt = 0; tt < TT; ++tt) {
            const float* trow = tile + tt * CP;   // uniform addr -> LDS broadcast
            float d = 0.f;
            #pragma unroll
            for (int c = 0; c < C; ++c) d += ps[c] * trow[c];
            int t = t0 + tb + tt;
            if (d > best) { best = d; bi = t; }   // strict > : first-max wins
        }
        __syncthreads();
    }
    pmax[((size_t)nn * NCHUNK + chunk) * S + s] = best;
    pidx[((size_t)nn * NCHUNK + chunk) * S + s] = bi;
}

// merge chunk partials -> ind, then the 19 loss terms; fixed-order block reduce
__global__ __launch_bounds__(256) void loss_k(const float* __restrict__ P,
                                              const float* __restrict__ pmax,
                                              const int* __restrict__ pidx,
                                              float* __restrict__ bsum) {
    __shared__ float red[256];
    int idx = blockIdx.x * 256 + threadIdx.x;   // 0 .. N*S-1
    int nn = idx / S;
    int s  = idx - nn * S;

    const float* pm = pmax + (size_t)nn * NCHUNK * S + s;
    const int*   pi = pidx + (size_t)nn * NCHUNK * S + s;
    float best = pm[0];
    int bi = pi[0];
    #pragma unroll
    for (int k = 1; k < NCHUNK; ++k) {
        float v = pm[(size_t)k * S];
        int   t = pi[(size_t)k * S];
        if (v > best) { best = v; bi = t; }   // ascending chunks: first-max wins
    }

    const float* Pn    = P + (size_t)nn * S * CP;
    const float* nrow  = Pn + (size_t)bi * CP;
    const float* ps    = Pn + (size_t)s  * CP;
    float acc = 0.f;
    #pragma unroll
    for (int c = 0; c < C; ++c) acc -= nrow[c] * logf(ps[c] + EPSF);

    red[threadIdx.x] = acc;
    __syncthreads();
    for (int off = 128; off > 0; off >>= 1) {
        if (threadIdx.x < off) red[threadIdx.x] += red[threadIdx.x + off];
        __syncthreads();
    }
    if (threadIdx.x == 0) bsum[blockIdx.x] = red[0];
}

__global__ void final_k(const float* __restrict__ bsum, float* __restrict__ out) {
    float t = 0.f;
    for (int i = 0; i < (N * S) / 256; ++i) t += bsum[i];   // fixed order
    out[0] = t / (float)(N * S * C);
}

extern "C" void kernel_launch(void* const* d_in, const int* in_sizes, int n_in,
                              void* d_out, int out_size, void* d_ws, size_t ws_size,
                              hipStream_t stream) {
    const float* out4d  = (const float*)d_in[0];
    const int*   sample = (const int*)d_in[1];

    float* P    = (float*)d_ws;                          // N*S*CP floats
    float* pmax = P + (size_t)N * S * CP;                // N*NCHUNK*S floats
    int*   pidx = (int*)(pmax + (size_t)N * NCHUNK * S); // N*NCHUNK*S ints
    float* bsum = (float*)(pidx + (size_t)N * NCHUNK * S); // 64 floats
    float* outp = (float*)d_out;

    gather_k<<<(N * S + 255) / 256, 256, 0, stream>>>(out4d, sample, P);
    argmax_k<<<N * NCHUNK * (S / STILE), 256, 0, stream>>>(P, pmax, pidx);
    loss_k<<<(N * S) / 256, 256, 0, stream>>>(P, pmax, pidx, bsum);
    final_k<<<1, 1, 0, stream>>>(bsum, outp);
}

// Round 2
// 99.525 us; speedup vs baseline: 3.1341x; 3.1341x over previous
//
#include <hip/hip_runtime.h>
#include <math.h>

#define N 2
#define C 19
#define H 512
#define W 512
#define PADC 50
#define WC 412
#define S 8192
#define CP 20            // padded channels (16B-aligned rows)
#define TS 4             // s-rows per thread (register tile)
#define BS 256           // threads per block
#define SROWS (TS * BS)  // 1024 s-rows per block
#define TT 128           // t rows staged in LDS per iteration
#define EPSF 1e-6f

// P[n][s][c] = output[n, c, 50 + sample[s]/412, 50 + sample[s]%412]
__global__ void gather_k(const float* __restrict__ out4d,
                         const int* __restrict__ sample,
                         float* __restrict__ P) {
    int idx = blockIdx.x * blockDim.x + threadIdx.x;   // 0 .. N*S-1
    if (idx >= N * S) return;
    int nn = idx / S;
    int s  = idx - nn * S;
    int smp = sample[s];
    int row = smp / WC;
    int col = smp - row * WC;
    int h = PADC + row, w = PADC + col;
    const float* base = out4d + ((size_t)nn * C) * H * W + (size_t)h * W + w;
    float* p = P + ((size_t)nn * S + s) * CP;
    #pragma unroll
    for (int c = 0; c < C; ++c) p[c] = base[(size_t)c * (H * W)];
    p[19] = 0.f;
}

// per (n, s-tile, t-chunk): best dot + (lowest) t index over the chunk.
// Each thread owns TS s-rows; t rows staged in LDS tiles of TT.
__global__ __launch_bounds__(256) void argmax_k(const float* __restrict__ P,
                                                float* __restrict__ pmax,
                                                int* __restrict__ pidx,
                                                int nchunk) {
    __shared__ float tile[TT * CP];   // 10 KiB
    int b = blockIdx.x;
    int chunk = b % nchunk;
    int stile = (b / nchunk) % (S / SROWS);
    int nn = b / (nchunk * (S / SROWS));
    int tid = threadIdx.x;
    int chunkLen = S / nchunk;
    int t0 = chunk * chunkLen;
    const float* Pn = P + (size_t)nn * S * CP;

    // load TS s-rows into registers (rows are 80B = 5 x float4)
    float ps[TS][C];
    int srow[TS];
    #pragma unroll
    for (int i = 0; i < TS; ++i) {
        srow[i] = stile * SROWS + i * BS + tid;
        const float4* r = (const float4*)(Pn + (size_t)srow[i] * CP);
        float4 a0 = r[0], a1 = r[1], a2 = r[2], a3 = r[3], a4 = r[4];
        ps[i][0]=a0.x;  ps[i][1]=a0.y;  ps[i][2]=a0.z;  ps[i][3]=a0.w;
        ps[i][4]=a1.x;  ps[i][5]=a1.y;  ps[i][6]=a1.z;  ps[i][7]=a1.w;
        ps[i][8]=a2.x;  ps[i][9]=a2.y;  ps[i][10]=a2.z; ps[i][11]=a2.w;
        ps[i][12]=a3.x; ps[i][13]=a3.y; ps[i][14]=a3.z; ps[i][15]=a3.w;
        ps[i][16]=a4.x; ps[i][17]=a4.y; ps[i][18]=a4.z;
    }

    float best[TS];
    int   bi[TS];
    #pragma unroll
    for (int i = 0; i < TS; ++i) { best[i] = -INFINITY; bi[i] = t0; }

    for (int tb = 0; tb < chunkLen; tb += TT) {
        // cooperative stage: TT rows * CP floats = 640 contiguous float4
        const float4* src = (const float4*)(Pn + (size_t)(t0 + tb) * CP);
        float4* dst = (float4*)tile;
        #pragma unroll
        for (int f = 0; f < TT * CP / 4 / BS + 1; ++f) {
            int k = f * BS + tid;
            if (k < TT * CP / 4) dst[k] = src[k];
        }
        __syncthreads();

        for (int tt = 0; tt < TT; ++tt) {
            const float4* t4 = (const float4*)(tile + tt * CP); // uniform -> broadcast
            float4 b0 = t4[0], b1 = t4[1], b2 = t4[2], b3 = t4[3], b4 = t4[4];
            float tr[C] = {b0.x,b0.y,b0.z,b0.w, b1.x,b1.y,b1.z,b1.w,
                           b2.x,b2.y,b2.z,b2.w, b3.x,b3.y,b3.z,b3.w,
                           b4.x,b4.y,b4.z};
            int t = t0 + tb + tt;
            #pragma unroll
            for (int i = 0; i < TS; ++i) {
                float d = 0.f;
                #pragma unroll
                for (int c = 0; c < C; ++c) d = fmaf(ps[i][c], tr[c], d);
                if (d > best[i]) { best[i] = d; bi[i] = t; }  // strict >: first-max
            }
        }
        __syncthreads();
    }
    #pragma unroll
    for (int i = 0; i < TS; ++i) {
        pmax[((size_t)nn * nchunk + chunk) * S + srow[i]] = best[i];
        pidx[((size_t)nn * nchunk + chunk) * S + srow[i]] = bi[i];
    }
}

// merge chunk partials -> ind, then the 19 loss terms; fixed-order block reduce
__global__ __launch_bounds__(256) void loss_k(const float* __restrict__ P,
                                              const float* __restrict__ pmax,
                                              const int* __restrict__ pidx,
                                              float* __restrict__ bsum,
                                              int nchunk) {
    __shared__ float red[256];
    int idx = blockIdx.x * 256 + threadIdx.x;   // 0 .. N*S-1
    int nn = idx / S;
    int s  = idx - nn * S;

    const float* pm = pmax + (size_t)nn * nchunk * S + s;
    const int*   pi = pidx + (size_t)nn * nchunk * S + s;
    float best = pm[0];
    int bi = pi[0];
    for (int k = 1; k < nchunk; ++k) {
        float v = pm[(size_t)k * S];
        int   t = pi[(size_t)k * S];
        if (v > best) { best = v; bi = t; }   // ascending chunks: first-max wins
    }

    const float* Pn    = P + (size_t)nn * S * CP;
    const float* nrow  = Pn + (size_t)bi * CP;
    const float* ps    = Pn + (size_t)s  * CP;
    float acc = 0.f;
    #pragma unroll
    for (int c = 0; c < C; ++c) acc -= nrow[c] * logf(ps[c] + EPSF);

    red[threadIdx.x] = acc;
    __syncthreads();
    for (int off = 128; off > 0; off >>= 1) {
        if (threadIdx.x < off) red[threadIdx.x] += red[threadIdx.x + off];
        __syncthreads();
    }
    if (threadIdx.x == 0) bsum[blockIdx.x] = red[0];
}

__global__ void final_k(const float* __restrict__ bsum, float* __restrict__ out) {
    float t = 0.f;
    for (int i = 0; i < (N * S) / 256; ++i) t += bsum[i];   // fixed order
    out[0] = t / (float)(N * S * C);
}

extern "C" void kernel_launch(void* const* d_in, const int* in_sizes, int n_in,
                              void* d_out, int out_size, void* d_ws, size_t ws_size,
                              hipStream_t stream) {
    const float* out4d  = (const float*)d_in[0];
    const int*   sample = (const int*)d_in[1];

    // pick the largest chunk count whose partials fit the workspace
    size_t pbytes = (size_t)N * S * CP * 4;
    int nchunk = 64;
    while (nchunk > 8) {
        size_t need = pbytes + (size_t)N * nchunk * S * 8 + 1024;
        if (need <= ws_size) break;
        nchunk >>= 1;
    }

    float* P    = (float*)d_ws;                               // N*S*CP floats
    float* pmax = P + (size_t)N * S * CP;                     // N*nchunk*S floats
    int*   pidx = (int*)(pmax + (size_t)N * nchunk * S);      // N*nchunk*S ints
    float* bsum = (float*)(pidx + (size_t)N * nchunk * S);    // 64 floats
    float* outp = (float*)d_out;

    gather_k<<<(N * S + 255) / 256, 256, 0, stream>>>(out4d, sample, P);
    argmax_k<<<N * nchunk * (S / SROWS), 256, 0, stream>>>(P, pmax, pidx, nchunk);
    loss_k<<<(N * S) / 256, 256, 0, stream>>>(P, pmax, pidx, bsum, nchunk);
    final_k<<<1, 1, 0, stream>>>(bsum, outp);
}